// Round 11
// baseline (1528.949 us; speedup 1.0000x reference)
//
#include <hip/hip_runtime.h>
#include <math.h>

// PCCNet: KNN(30) + per-neighbor MLP(6->64->64) + 3-scale prefix softmax attention.
// Round 11: round-10 bitmask knn with the per-query selection loop FULLY UNROLLED
// (compile-time qi) -> no runtime-indexed register arrays -> no scratch spill
// (round-10 counters showed 233MB scratch writes from the unroll-1 loop).

#define NB 8
#define NPT 4096
#define KMAXK 30
#define ROWS (NB * NPT)
#define QW 4  // queries per wave (knn)

typedef __attribute__((ext_vector_type(8))) short short8v;
typedef __attribute__((ext_vector_type(4))) float float4v;
typedef __attribute__((ext_vector_type(2))) float float2v;
typedef __attribute__((ext_vector_type(4))) int int4v;

__device__ __forceinline__ unsigned long long shflx64(unsigned long long v, int m) {
  unsigned lo = (unsigned)__shfl_xor((int)(unsigned)(v & 0xFFFFFFFFull), m, 64);
  unsigned hi = (unsigned)__shfl_xor((int)(unsigned)(v >> 32), m, 64);
  return ((unsigned long long)hi << 32) | (unsigned long long)lo;
}

__device__ __forceinline__ short f2bf(float x) {  // f32 -> bf16 RNE
  unsigned u = __float_as_uint(x);
  return (short)((u + 0x7FFFu + ((u >> 16) & 1u)) >> 16);
}

__device__ __forceinline__ int cvtpk(float lo, float hi) {  // packed bf16 RNE
  int r;
  asm("v_cvt_pk_bf16_f32 %0, %1, %2" : "=v"(r) : "v"(lo), "v"(hi));
  return r;
}

__device__ __forceinline__ unsigned ordkey(float f) {  // monotonic u32 of f32
  const unsigned bits = __float_as_uint(f);
  return bits ^ ((unsigned)((int)bits >> 31) | 0x80000000u);
}

__device__ __forceinline__ float sbcast(float v) {  // force wave-uniform -> SGPR
  return __int_as_float(__builtin_amdgcn_readfirstlane(__float_as_int(v)));
}

// ---------------- Kernel 0: pack (x,y,z,|x|^2) + pack W2 bf16 fragments ----
__global__ __launch_bounds__(256) void prep_kernel(const float* __restrict__ x,
                                                   const float* __restrict__ w2,
                                                   float4v* __restrict__ xq,
                                                   short8v* __restrict__ w2bf) {
  const int i = blockIdx.x * 256 + threadIdx.x;
  if (i < ROWS) {
    const int b = i >> 12, m = i & (NPT - 1);
    const float* xb = x + (size_t)b * 3 * NPT;
    const float y0 = xb[m], y1 = xb[NPT + m], y2 = xb[2 * NPT + m];
    const float xx = y0 * y0 + y1 * y1 + y2 * y2;
    xq[i] = (float4v){y0, y1, y2, xx};
  }
  if (blockIdx.x == ROWS / 256) {
#pragma unroll
    for (int u = 0; u < 2; ++u) {
      const int v = threadIdx.x * 2 + u;
      const int lane = v & 63, fi = v >> 6;
      const int kt = fi >> 2, nt = fi & 3;
      const int q = lane & 15, g = lane >> 4;
      const float* src = w2 + (nt * 16 + q) * 64 + kt * 32 + g * 8;
      short8v tt;
#pragma unroll
      for (int e = 0; e < 8; ++e) tt[e] = f2bf(src[e]);
      w2bf[v] = tt;
    }
  }
}

// ---------------- Kernel 1: exact top-30 neighbor indices, 4 queries/wave --
__global__ __launch_bounds__(256, 6) void knn_kernel(const float4v* __restrict__ xq,
                                                     int* __restrict__ knn) {
  __shared__ unsigned long long cbuf[4][QW][128];  // 16 KB, wave-private regions
  const int wv = threadIdx.x >> 6;
  const int lane = threadIdx.x & 63;
  const int row0 = ((blockIdx.x << 2) + wv) * QW;
  const int b = row0 >> 12;
  const int n0 = row0 & (NPT - 1);
  const float4v* xqb = xq + ((size_t)b << 12);
  const float4v* pc = xqb + lane;

  float qx[QW], qy[QW], qz[QW], qq[QW];
#pragma unroll
  for (int qi = 0; qi < QW; ++qi) {
    const float4v qv = xqb[n0 + qi];
    qx[qi] = sbcast(qv[0]);
    qy[qi] = sbcast(qv[1]);
    qz[qi] = sbcast(qv[2]);
    qq[qi] = sbcast(qv[3]);
  }
  float2v qxp[2], qyp[2], qzp[2], qqp[2];
#pragma unroll
  for (int p = 0; p < 2; ++p) {
    qxp[p] = (float2v){qx[2 * p], qx[2 * p + 1]};
    qyp[p] = (float2v){qy[2 * p], qy[2 * p + 1]};
    qzp[p] = (float2v){qz[2 * p], qz[2 * p + 1]};
    qqp[p] = (float2v){qq[2 * p], qq[2 * p + 1]};
  }

  // ---- pass 1: per-query lane-max, unrolled x4 (round-6 proven) ----
  float2v kmaxp[2];
  kmaxp[0] = (float2v){-3.0e38f, -3.0e38f};
  kmaxp[1] = (float2v){-3.0e38f, -3.0e38f};
  for (int j = 0; j < 64; j += 4) {
    float4v cL[4];
#pragma unroll
    for (int u = 0; u < 4; ++u) cL[u] = pc[(size_t)(j + u) << 6];
#pragma unroll
    for (int u = 0; u < 4; ++u) {
      const float4v c = cL[u];
      const float2v cx = (float2v){c[0], c[0]};
      const float2v cy = (float2v){c[1], c[1]};
      const float2v cz = (float2v){c[2], c[2]};
      const float2v cw = (float2v){c[3], c[3]};
#pragma unroll
      for (int p = 0; p < 2; ++p) {
        float2v inner = cx * qxp[p];
        inner = __builtin_elementwise_fma(cy, qyp[p], inner);
        inner = __builtin_elementwise_fma(cz, qzp[p], inner);
        const float2v pd = (inner + inner) - qqp[p] - cw;
        kmaxp[p] = __builtin_elementwise_max(kmaxp[p], pd);
      }
    }
  }
  const float kmaxs[QW] = {kmaxp[0][0], kmaxp[0][1], kmaxp[1][0], kmaxp[1][1]};

  float thr[QW];
#pragma unroll
  for (int qi = 0; qi < QW; ++qi) {
    float v = kmaxs[qi];
#pragma unroll
    for (int kk = 2; kk <= 64; kk <<= 1) {
#pragma unroll
      for (int jj = 32; jj >= 1; jj >>= 1) {
        if (jj < kk) {
          const float o = __shfl_xor(v, jj, 64);
          const bool up = ((lane & kk) == 0);
          const bool takeMax = (((lane & jj) != 0) == up);
          v = takeMax ? fmaxf(v, o) : fminf(v, o);
        }
      }
    }
    thr[qi] = sbcast(__shfl(v, 34, 64)) - 1.0e-4f;  // eps: survivor superset only
  }

  // ---- pass 2: per-lane VGPR bitmask build (no LDS, ~3 VALU/pair) ----
  unsigned bmlo[QW] = {0u, 0u, 0u, 0u};
  unsigned bmhi[QW] = {0u, 0u, 0u, 0u};
#pragma unroll
  for (int half = 0; half < 2; ++half) {
    for (int j = half * 32; j < half * 32 + 32; j += 4) {
      float4v cL[4];
#pragma unroll
      for (int u = 0; u < 4; ++u) cL[u] = pc[(size_t)(j + u) << 6];
      float2v pdp[4][2];
#pragma unroll
      for (int u = 0; u < 4; ++u) {
        const float4v c = cL[u];
        const float2v cx = (float2v){c[0], c[0]};
        const float2v cy = (float2v){c[1], c[1]};
        const float2v cz = (float2v){c[2], c[2]};
        const float2v cw = (float2v){c[3], c[3]};
#pragma unroll
        for (int p = 0; p < 2; ++p) {
          float2v inner = cx * qxp[p];
          inner = __builtin_elementwise_fma(cy, qyp[p], inner);
          inner = __builtin_elementwise_fma(cz, qzp[p], inner);
          pdp[u][p] = (inner + inner) - qqp[p] - cw;
        }
      }
#pragma unroll
      for (int u = 0; u < 4; ++u) {
        const unsigned sh = 1u << ((j + u) & 31);  // shared across queries
#pragma unroll
        for (int qi = 0; qi < QW; ++qi) {
          const unsigned bit = (pdp[u][qi >> 1][qi & 1] >= thr[qi]) ? sh : 0u;
          if (half == 0) bmlo[qi] |= bit;
          else bmhi[qi] |= bit;
        }
      }
    }
  }

  // ---- per-query: prefix, extract survivors (exact keys), sort ----
  // FULLY UNROLLED so qi is compile-time: no runtime-indexed register arrays
  // (round-10 lesson: unroll-1 here spilled qx/thr/bm* to scratch, 233MB HBM).
#pragma unroll
  for (int qi = 0; qi < QW; ++qi) {
    const int cntL = __popc(bmlo[qi]) + __popc(bmhi[qi]);
    int pfx = cntL;
#pragma unroll
    for (int d = 1; d < 64; d <<= 1) {
      const int t = __shfl_up(pfx, d, 64);
      if (lane >= d) pfx += t;
    }
    const int total = __builtin_amdgcn_readfirstlane(__shfl(pfx, 63, 64));
    const int excl = pfx - cntL;
    const int outbase = (row0 + qi) * 32;
    unsigned long long* cb = &cbuf[wv][qi][0];

    if (total >= KMAXK && total <= 128) {
      int pos = excl;
      unsigned ml = bmlo[qi];
      while (ml) {
        const int bj = (int)__builtin_ctz(ml);
        ml &= ml - 1u;
        const int mm = (bj << 6) + lane;
        const float4v c = xqb[mm];
        float inner = c[0] * qx[qi];
        inner = fmaf(c[1], qy[qi], inner);
        inner = fmaf(c[2], qz[qi], inner);
        const float pd = (inner + inner) - qq[qi] - c[3];
        cb[pos++] = ((unsigned long long)ordkey(pd) << 32) | (unsigned)(4095 - mm);
      }
      unsigned mh = bmhi[qi];
      while (mh) {
        const int bj = (int)__builtin_ctz(mh) + 32;
        mh &= mh - 1u;
        const int mm = (bj << 6) + lane;
        const float4v c = xqb[mm];
        float inner = c[0] * qx[qi];
        inner = fmaf(c[1], qy[qi], inner);
        inner = fmaf(c[2], qz[qi], inner);
        const float pd = (inner + inner) - qq[qi] - c[3];
        cb[pos++] = ((unsigned long long)ordkey(pd) << 32) | (unsigned)(4095 - mm);
      }
      asm volatile("" ::: "memory");

      if (total <= 64) {
        // 64-lane bitonic sort ascending of packed (key, 4095-m)
        unsigned long long val = (lane < total) ? cb[lane] : 0ull;
#pragma unroll
        for (int kk = 2; kk <= 64; kk <<= 1) {
#pragma unroll
          for (int jj = 32; jj >= 1; jj >>= 1) {
            if (jj < kk) {
              const unsigned long long o = shflx64(val, jj);
              const bool up = ((lane & kk) == 0);
              const bool takeMax = (((lane & jj) != 0) == up);
              const unsigned long long mx = val > o ? val : o;
              const unsigned long long mn = val > o ? o : val;
              val = takeMax ? mx : mn;
            }
          }
        }
        const int rank = 63 - lane;
        if (rank < KMAXK) {
          const int m = 4095 - (int)(val & 0xFFFFFFFFull);
          knn[outbase + rank] = m;
        }
      } else {
        // 64 < total <= 128: iterative wave-argmax over compacted buffer
        for (int r = 0; r < KMAXK; ++r) {
          unsigned long long lmax = 0ull;
          int lpos = -1;
          for (int p = lane; p < total; p += 64) {
            const unsigned long long q2 = cb[p];
            if (q2 > lmax) { lmax = q2; lpos = p; }
          }
          unsigned long long g = lmax;
#pragma unroll
          for (int s = 32; s >= 1; s >>= 1) {
            const unsigned long long o = shflx64(g, s);
            g = o > g ? o : g;
          }
          const unsigned long long pm = __ballot(lmax == g && lpos >= 0);
          const int lowlane = (int)(__ffsll((unsigned long long)pm) - 1);
          if (lane == lowlane) cb[lpos] = 0ull;
          if (lane == 0) knn[outbase + r] = 4095 - (int)(g & 0xFFFFFFFFull);
        }
      }
    } else {
      // fallback (pathological only): exact scan-select from global, 30 rounds
      unsigned long long prev = ~0ull;
      for (int r = 0; r < KMAXK; ++r) {
        unsigned long long best = 0ull;
        for (int j = 0; j < 64; ++j) {
          const int m = (j << 6) + lane;
          const float4v cc = xqb[m];
          float inner = cc[0] * qx[qi];
          inner = fmaf(cc[1], qy[qi], inner);
          inner = fmaf(cc[2], qz[qi], inner);
          const float pd = (inner + inner) - qq[qi] - cc[3];
          const unsigned long long key =
              ((unsigned long long)ordkey(pd) << 32) | (unsigned)(4095 - m);
          if (key < prev && key > best) best = key;
        }
#pragma unroll
        for (int s = 32; s >= 1; s >>= 1) {
          const unsigned long long o = shflx64(best, s);
          best = o > best ? o : best;
        }
        if (lane == 0) knn[outbase + r] = 4095 - (int)(best & 0xFFFFFFFFull);
        prev = best;
      }
    }
  }
}

// ---------------- MLP epilogue (per point, math identical to round 6) ------
__device__ __forceinline__ void mlp_epilogue(float4v (&dfr)[2][4],
                                             const float* s2r, const float* be2r,
                                             const float* war, float sa, float ba0,
                                             float bga0, int q, int g,
                                             float* __restrict__ outp) {
  float part[2][4];
#pragma unroll
  for (int mt = 0; mt < 2; ++mt)
#pragma unroll
    for (int r = 0; r < 4; ++r) part[mt][r] = 0.f;
#pragma unroll
  for (int mt = 0; mt < 2; ++mt)
#pragma unroll
    for (int nt = 0; nt < 4; ++nt) {
      float4v d = dfr[mt][nt];
#pragma unroll
      for (int r = 0; r < 4; ++r) {
        float h2 = fmaf(d[r], s2r[nt], be2r[nt]);
        h2 = fmaxf(h2, 0.2f * h2);
        d[r] = h2;
        part[mt][r] = fmaf(war[nt], h2, part[mt][r]);
      }
      dfr[mt][nt] = d;
    }
#pragma unroll
  for (int mt = 0; mt < 2; ++mt)
#pragma unroll
    for (int r = 0; r < 4; ++r) {
      float p = part[mt][r];
      p += __shfl_xor(p, 1, 64);
      p += __shfl_xor(p, 2, 64);
      p += __shfl_xor(p, 4, 64);
      p += __shfl_xor(p, 8, 64);
      part[mt][r] = p;
    }

  const int mrow = g * 4;
  float sc0[4], sc1[4];
  float mloc = -3.0e38f;
#pragma unroll
  for (int r = 0; r < 4; ++r) {
    float a = fmaf(part[0][r] + ba0, sa, bga0);
    a = fmaxf(a, 0.2f * a);
    sc0[r] = a;
    mloc = fmaxf(mloc, a);
  }
#pragma unroll
  for (int r = 0; r < 4; ++r) {
    float a = fmaf(part[1][r] + ba0, sa, bga0);
    a = fmaxf(a, 0.2f * a);
    sc1[r] = a;
    if (mrow + r < 14) mloc = fmaxf(mloc, a);
  }
  mloc = fmaxf(mloc, __shfl_xor(mloc, 16, 64));
  mloc = fmaxf(mloc, __shfl_xor(mloc, 32, 64));

  float e0[4], e1[4];
  float l10 = 0.f, l20 = 0.f, l30 = 0.f;
#pragma unroll
  for (int r = 0; r < 4; ++r) {
    const float vv = expf(sc0[r] - mloc);
    e0[r] = vv;
    l30 += vv;
    l20 += vv;
    if (mrow + r < 10) l10 += vv;
  }
#pragma unroll
  for (int r = 0; r < 4; ++r) {
    const float vv = (mrow + r < 14) ? expf(sc1[r] - mloc) : 0.f;
    e1[r] = vv;
    l30 += vv;
    if (mrow + r < 4) l20 += vv;
  }
  l10 += __shfl_xor(l10, 16, 64); l10 += __shfl_xor(l10, 32, 64);
  l20 += __shfl_xor(l20, 16, 64); l20 += __shfl_xor(l20, 32, 64);
  l30 += __shfl_xor(l30, 16, 64); l30 += __shfl_xor(l30, 32, 64);
  const float i10 = 1.0f / l10, i20 = 1.0f / l20, i30 = 1.0f / l30;
  const float third = 1.0f / 3.0f;

  float wgt0[4], wgt1[4];
#pragma unroll
  for (int r = 0; r < 4; ++r) {
    wgt0[r] = e0[r] * (((mrow + r < 10) ? i10 : 0.f) + i20 + i30) * third;
    wgt1[r] = e1[r] * (((mrow + r < 4) ? i20 : 0.f) + i30) * third;
  }

  float acc[4] = {0.f, 0.f, 0.f, 0.f};
#pragma unroll
  for (int nt = 0; nt < 4; ++nt) {
#pragma unroll
    for (int r = 0; r < 4; ++r) {
      acc[nt] = fmaf(wgt0[r], dfr[0][nt][r], acc[nt]);
      acc[nt] = fmaf(wgt1[r], dfr[1][nt][r], acc[nt]);
    }
  }
#pragma unroll
  for (int nt = 0; nt < 4; ++nt) {
    acc[nt] += __shfl_xor(acc[nt], 16, 64);
    acc[nt] += __shfl_xor(acc[nt], 32, 64);
  }
  const float val = (g == 0) ? acc[0] : (g == 1) ? acc[1] : (g == 2) ? acc[2] : acc[3];
  outp[(size_t)(q + 16 * g) * NPT] = val;
}

// ---------------- Kernel 2: MFMA MLP, 2 points per wave --------------------
__global__ __launch_bounds__(256, 4) void pcc_mlp_mfma(
    const float4v* __restrict__ xq, const float* __restrict__ w1,
    const float* __restrict__ g1, const float* __restrict__ b1,
    const short8v* __restrict__ w2bf, const float* __restrict__ g2,
    const float* __restrict__ b2, const float* __restrict__ wa,
    const float* __restrict__ ba, const float* __restrict__ ga,
    const float* __restrict__ bga, const int* __restrict__ knn,
    float* __restrict__ out) {
  __shared__ float w1s[64][8];  // per ch: w1d*s1 (3), w1c*s1 (3), be1, 0
  const int tid = threadIdx.x;
  const float invs = 1.0f / sqrtf(1.0f + 1e-5f);
  for (int idx = tid; idx < 512; idx += 256) {
    const int c = idx >> 3, s = idx & 7;
    float v = 0.f;
    if (s < 6) v = w1[c * 6 + s] * (g1[c] * invs);
    else if (s == 6) v = b1[c];
    w1s[c][s] = v;
  }
  __syncthreads();

  const int wv = tid >> 6, lane = tid & 63;
  const int q = lane & 15, g = lane >> 4;
  const int wid = (blockIdx.x << 2) + wv;
  const int rowA = wid * 2;  // two consecutive points, same batch
  const int b = rowA >> 12;
  const int nA = rowA & (NPT - 1), nB = nA + 1;
  const float4v* xqb = xq + ((size_t)b << 12);

  const float4v qvA = xqb[nA];
  const float xnA0 = qvA[0], xnA1 = qvA[1], xnA2 = qvA[2];
  const float4v qvB = xqb[nB];
  const float xnB0 = qvB[0], xnB1 = qvB[1], xnB2 = qvB[2];

  const int jA0 = knn[rowA * 32 + q];
  const int jB0 = knn[(rowA + 1) * 32 + q];
  const float4v cA0 = xqb[jA0];
  const float4v cB0 = xqb[jB0];
  float aA1x = xnA0, aA1y = xnA1, aA1z = xnA2;  // pad row: d=0, finite
  float aB1x = xnB0, aB1y = xnB1, aB1z = xnB2;
  if (q < 14) {
    const int jA1 = knn[rowA * 32 + 16 + q];
    const int jB1 = knn[(rowA + 1) * 32 + 16 + q];
    const float4v cA1 = xqb[jA1];
    const float4v cB1 = xqb[jB1];
    aA1x = cA1[0]; aA1y = cA1[1]; aA1z = cA1[2];
    aB1x = cB1[0]; aB1y = cB1[1]; aB1z = cB1[2];
  }
  const float dA0x = cA0[0] - xnA0, dA0y = cA0[1] - xnA1, dA0z = cA0[2] - xnA2;
  const float dA1x = aA1x - xnA0, dA1y = aA1y - xnA1, dA1z = aA1z - xnA2;
  const float dB0x = cB0[0] - xnB0, dB0y = cB0[1] - xnB1, dB0z = cB0[2] - xnB2;
  const float dB1x = aB1x - xnB0, dB1y = aB1y - xnB1, dB1z = aB1z - xnB2;

  float4v dfrA[2][4], dfrB[2][4];
#pragma unroll
  for (int mt = 0; mt < 2; ++mt)
#pragma unroll
    for (int nt = 0; nt < 4; ++nt) {
      dfrA[mt][nt] = (float4v){0.f, 0.f, 0.f, 0.f};
      dfrB[mt][nt] = (float4v){0.f, 0.f, 0.f, 0.f};
    }

#pragma unroll
  for (int kt = 0; kt < 2; ++kt) {
    short8v bfk[4];
#pragma unroll
    for (int nt = 0; nt < 4; ++nt) bfk[nt] = w2bf[((kt << 2) + nt) * 64 + lane];
    int4v aA0i, aA1i, aB0i, aB1i;
#pragma unroll
    for (int e2 = 0; e2 < 4; ++e2) {
      float hA0[2], hA1[2], hB0[2], hB1[2];
#pragma unroll
      for (int u = 0; u < 2; ++u) {
        const int c = kt * 32 + g * 8 + e2 * 2 + u;
        const float4v wlo = *(const float4v*)&w1s[c][0];
        const float4v whi = *(const float4v*)&w1s[c][4];
        const float hcbA = fmaf(wlo[3], xnA0, fmaf(whi[0], xnA1, fmaf(whi[1], xnA2, whi[2])));
        float h = fmaf(wlo[0], dA0x, fmaf(wlo[1], dA0y, fmaf(wlo[2], dA0z, hcbA)));
        hA0[u] = fmaxf(h, 0.2f * h);
        h = fmaf(wlo[0], dA1x, fmaf(wlo[1], dA1y, fmaf(wlo[2], dA1z, hcbA)));
        hA1[u] = fmaxf(h, 0.2f * h);
        const float hcbB = fmaf(wlo[3], xnB0, fmaf(whi[0], xnB1, fmaf(whi[1], xnB2, whi[2])));
        h = fmaf(wlo[0], dB0x, fmaf(wlo[1], dB0y, fmaf(wlo[2], dB0z, hcbB)));
        hB0[u] = fmaxf(h, 0.2f * h);
        h = fmaf(wlo[0], dB1x, fmaf(wlo[1], dB1y, fmaf(wlo[2], dB1z, hcbB)));
        hB1[u] = fmaxf(h, 0.2f * h);
      }
      aA0i[e2] = cvtpk(hA0[0], hA0[1]);
      aA1i[e2] = cvtpk(hA1[0], hA1[1]);
      aB0i[e2] = cvtpk(hB0[0], hB0[1]);
      aB1i[e2] = cvtpk(hB1[0], hB1[1]);
    }
    const short8v afA0 = __builtin_bit_cast(short8v, aA0i);
    const short8v afA1 = __builtin_bit_cast(short8v, aA1i);
    const short8v afB0 = __builtin_bit_cast(short8v, aB0i);
    const short8v afB1 = __builtin_bit_cast(short8v, aB1i);
#pragma unroll
    for (int nt = 0; nt < 4; ++nt) {
      dfrA[0][nt] = __builtin_amdgcn_mfma_f32_16x16x32_bf16(afA0, bfk[nt], dfrA[0][nt], 0, 0, 0);
      dfrA[1][nt] = __builtin_amdgcn_mfma_f32_16x16x32_bf16(afA1, bfk[nt], dfrA[1][nt], 0, 0, 0);
      dfrB[0][nt] = __builtin_amdgcn_mfma_f32_16x16x32_bf16(afB0, bfk[nt], dfrB[0][nt], 0, 0, 0);
      dfrB[1][nt] = __builtin_amdgcn_mfma_f32_16x16x32_bf16(afB1, bfk[nt], dfrB[1][nt], 0, 0, 0);
    }
  }

  float s2r[4], be2r[4], war[4];
#pragma unroll
  for (int nt = 0; nt < 4; ++nt) {
    s2r[nt] = g2[q + 16 * nt] * invs;
    be2r[nt] = b2[q + 16 * nt];
    war[nt] = wa[q + 16 * nt];
  }
  const float sa = ga[0] * invs, ba0 = ba[0], bga0 = bga[0];

  float* outbB = out + ((size_t)b * 64) * NPT;
  mlp_epilogue(dfrA, s2r, be2r, war, sa, ba0, bga0, q, g, outbB + nA);
  mlp_epilogue(dfrB, s2r, be2r, war, sa, ba0, bga0, q, g, outbB + nB);
}

extern "C" void kernel_launch(void* const* d_in, const int* in_sizes, int n_in,
                              void* d_out, int out_size, void* d_ws, size_t ws_size,
                              hipStream_t stream) {
  const float* x = (const float*)d_in[0];
  const float* w1 = (const float*)d_in[1];
  const float* g1 = (const float*)d_in[2];
  const float* b1 = (const float*)d_in[3];
  const float* w2 = (const float*)d_in[4];
  const float* g2 = (const float*)d_in[5];
  const float* b2 = (const float*)d_in[6];
  const float* wa = (const float*)d_in[7];
  const float* ba = (const float*)d_in[8];
  const float* ga = (const float*)d_in[9];
  const float* bga = (const float*)d_in[10];
  float* out = (float*)d_out;

  float4v* xq = (float4v*)d_ws;                         // 512 KB
  int* knn = (int*)((char*)d_ws + ROWS * 16);           // 4 MB
  short8v* w2bf = (short8v*)((char*)d_ws + ROWS * 16 + ROWS * 32 * 4);  // 8 KB

  prep_kernel<<<dim3(ROWS / 256 + 1), dim3(256), 0, stream>>>(x, w2, xq, w2bf);
  knn_kernel<<<dim3(ROWS / (4 * QW)), dim3(256), 0, stream>>>(xq, knn);
  pcc_mlp_mfma<<<dim3(ROWS / 8), dim3(256), 0, stream>>>(
      xq, w1, g1, b1, w2bf, g2, b2, wa, ba, ga, bga, knn, out);
}

// Round 12
// 129.150 us; speedup vs baseline: 11.8386x; 11.8386x over previous
//
#include <hip/hip_runtime.h>
#include <math.h>

// PCCNet: KNN(30) + per-neighbor MLP(6->64->64) + 3-scale prefix softmax attention.
// Round 12: round-8 structure (proven: knn 92us @ 28 VGPR, zero spill) with ONE
// change: prefix-rank via v_mbcnt_lo/hi (2 VALU) instead of popcll(mask&lanemask).
// Rounds 7/9/10/11 all showed pass-2 restructures trigger pathological codegen;
// the ballot form is the robust optimum for this kernel.

#define NB 8
#define NPT 4096
#define KMAXK 30
#define ROWS (NB * NPT)
#define QW 4     // queries per wave (knn)
#define SCAP 96  // survivor cap per query (observed ~48)

typedef __attribute__((ext_vector_type(8))) short short8v;
typedef __attribute__((ext_vector_type(4))) float float4v;
typedef __attribute__((ext_vector_type(2))) float float2v;
typedef __attribute__((ext_vector_type(4))) int int4v;

__device__ __forceinline__ unsigned long long shflx64(unsigned long long v, int m) {
  unsigned lo = (unsigned)__shfl_xor((int)(unsigned)(v & 0xFFFFFFFFull), m, 64);
  unsigned hi = (unsigned)__shfl_xor((int)(unsigned)(v >> 32), m, 64);
  return ((unsigned long long)hi << 32) | (unsigned long long)lo;
}

__device__ __forceinline__ short f2bf(float x) {  // f32 -> bf16 RNE
  unsigned u = __float_as_uint(x);
  return (short)((u + 0x7FFFu + ((u >> 16) & 1u)) >> 16);
}

__device__ __forceinline__ int cvtpk(float lo, float hi) {  // packed bf16 RNE
  int r;
  asm("v_cvt_pk_bf16_f32 %0, %1, %2" : "=v"(r) : "v"(lo), "v"(hi));
  return r;
}

__device__ __forceinline__ unsigned ordkey(float f) {  // monotonic u32 of f32
  const unsigned bits = __float_as_uint(f);
  return bits ^ ((unsigned)((int)bits >> 31) | 0x80000000u);
}

__device__ __forceinline__ float sbcast(float v) {  // force wave-uniform -> SGPR
  return __int_as_float(__builtin_amdgcn_readfirstlane(__float_as_int(v)));
}

// popcount of mask bits strictly below this lane (v_mbcnt_lo + v_mbcnt_hi).
__device__ __forceinline__ int mbcnt64(unsigned long long mask) {
  return (int)__builtin_amdgcn_mbcnt_hi(
      (unsigned)(mask >> 32),
      __builtin_amdgcn_mbcnt_lo((unsigned)(mask & 0xFFFFFFFFull), 0u));
}

// ---------------- Kernel 0: pack (x,y,z,|x|^2) + pack W2 bf16 fragments ----
__global__ __launch_bounds__(256) void prep_kernel(const float* __restrict__ x,
                                                   const float* __restrict__ w2,
                                                   float4v* __restrict__ xq,
                                                   short8v* __restrict__ w2bf) {
  const int i = blockIdx.x * 256 + threadIdx.x;
  if (i < ROWS) {
    const int b = i >> 12, m = i & (NPT - 1);
    const float* xb = x + (size_t)b * 3 * NPT;
    const float y0 = xb[m], y1 = xb[NPT + m], y2 = xb[2 * NPT + m];
    const float xx = y0 * y0 + y1 * y1 + y2 * y2;
    xq[i] = (float4v){y0, y1, y2, xx};
  }
  if (blockIdx.x == ROWS / 256) {
#pragma unroll
    for (int u = 0; u < 2; ++u) {
      const int v = threadIdx.x * 2 + u;
      const int lane = v & 63, fi = v >> 6;
      const int kt = fi >> 2, nt = fi & 3;
      const int q = lane & 15, g = lane >> 4;
      const float* src = w2 + (nt * 16 + q) * 64 + kt * 32 + g * 8;
      short8v tt;
#pragma unroll
      for (int e = 0; e < 8; ++e) tt[e] = f2bf(src[e]);
      w2bf[v] = tt;
    }
  }
}

// ---------------- Kernel 1: exact top-30 neighbor indices, 4 queries/wave --
__global__ __launch_bounds__(256, 6) void knn_kernel(const float4v* __restrict__ xq,
                                                     int* __restrict__ knn) {
  __shared__ unsigned long long buf[4][QW][SCAP];  // 12 KB
  const int wv = threadIdx.x >> 6;
  const int lane = threadIdx.x & 63;
  const int row0 = ((blockIdx.x << 2) + wv) * QW;
  const int b = row0 >> 12;
  const int n0 = row0 & (NPT - 1);
  const float4v* xqb = xq + ((size_t)b << 12);
  const float4v* pc = xqb + lane;

  float qx[QW], qy[QW], qz[QW], qq[QW];
#pragma unroll
  for (int qi = 0; qi < QW; ++qi) {
    const float4v qv = xqb[n0 + qi];
    qx[qi] = sbcast(qv[0]);
    qy[qi] = sbcast(qv[1]);
    qz[qi] = sbcast(qv[2]);
    qq[qi] = sbcast(qv[3]);
  }
  float2v qxp[2], qyp[2], qzp[2], qqp[2];
#pragma unroll
  for (int p = 0; p < 2; ++p) {
    qxp[p] = (float2v){qx[2 * p], qx[2 * p + 1]};
    qyp[p] = (float2v){qy[2 * p], qy[2 * p + 1]};
    qzp[p] = (float2v){qz[2 * p], qz[2 * p + 1]};
    qqp[p] = (float2v){qq[2 * p], qq[2 * p + 1]};
  }

  // ---- pass 1: per-query lane-max, unrolled x4 ----
  float2v kmaxp[2];
  kmaxp[0] = (float2v){-3.0e38f, -3.0e38f};
  kmaxp[1] = (float2v){-3.0e38f, -3.0e38f};
  for (int j = 0; j < 64; j += 4) {
    float4v cL[4];
#pragma unroll
    for (int u = 0; u < 4; ++u) cL[u] = pc[(size_t)(j + u) << 6];
#pragma unroll
    for (int u = 0; u < 4; ++u) {
      const float4v c = cL[u];
      const float2v cx = (float2v){c[0], c[0]};
      const float2v cy = (float2v){c[1], c[1]};
      const float2v cz = (float2v){c[2], c[2]};
      const float2v cw = (float2v){c[3], c[3]};
#pragma unroll
      for (int p = 0; p < 2; ++p) {
        float2v inner = cx * qxp[p];
        inner = __builtin_elementwise_fma(cy, qyp[p], inner);
        inner = __builtin_elementwise_fma(cz, qzp[p], inner);
        const float2v pd = (inner + inner) - qqp[p] - cw;
        kmaxp[p] = __builtin_elementwise_max(kmaxp[p], pd);
      }
    }
  }
  const float kmaxs[QW] = {kmaxp[0][0], kmaxp[0][1], kmaxp[1][0], kmaxp[1][1]};

  float thr[QW];
#pragma unroll
  for (int qi = 0; qi < QW; ++qi) {
    float v = kmaxs[qi];
#pragma unroll
    for (int kk = 2; kk <= 64; kk <<= 1) {
#pragma unroll
      for (int jj = 32; jj >= 1; jj >>= 1) {
        if (jj < kk) {
          const float o = __shfl_xor(v, jj, 64);
          const bool up = ((lane & kk) == 0);
          const bool takeMax = (((lane & jj) != 0) == up);
          v = takeMax ? fmaxf(v, o) : fminf(v, o);
        }
      }
    }
    thr[qi] = sbcast(__shfl(v, 34, 64)) - 1.0e-4f;  // eps: survivor superset only
  }

  // ---- pass 2: recompute + ballot-compact (mbcnt prefix rank), unrolled x4 ----
  int cnt[QW];
#pragma unroll
  for (int qi = 0; qi < QW; ++qi) cnt[qi] = 0;
  for (int j = 0; j < 64; j += 4) {
    float4v cL[4];
#pragma unroll
    for (int u = 0; u < 4; ++u) cL[u] = pc[(size_t)(j + u) << 6];
    float2v pdp[4][2];
#pragma unroll
    for (int u = 0; u < 4; ++u) {
      const float4v c = cL[u];
      const float2v cx = (float2v){c[0], c[0]};
      const float2v cy = (float2v){c[1], c[1]};
      const float2v cz = (float2v){c[2], c[2]};
      const float2v cw = (float2v){c[3], c[3]};
#pragma unroll
      for (int p = 0; p < 2; ++p) {
        float2v inner = cx * qxp[p];
        inner = __builtin_elementwise_fma(cy, qyp[p], inner);
        inner = __builtin_elementwise_fma(cz, qzp[p], inner);
        pdp[u][p] = (inner + inner) - qqp[p] - cw;
      }
    }
#pragma unroll
    for (int u = 0; u < 4; ++u) {
      const int m = ((j + u) << 6) + lane;
#pragma unroll
      for (int qi = 0; qi < QW; ++qi) {
        const float pd = pdp[u][qi >> 1][qi & 1];
        const bool pred = pd >= thr[qi];
        const unsigned long long mask = __ballot(pred);
        if (pred) {
          const int pos = cnt[qi] + mbcnt64(mask);
          if (pos < SCAP) {
            buf[wv][qi][pos] = ((unsigned long long)ordkey(pd) << 32) | (unsigned)(4095 - m);
          }
        }
        cnt[qi] += (int)__popcll(mask);
      }
    }
  }

  // ---- selection per query ----
#pragma unroll 1
  for (int qi = 0; qi < QW; ++qi) {
    const int c = cnt[qi];
    const int outbase = (row0 + qi) * 32;
    if (c >= KMAXK && c <= 64) {
      unsigned long long val = (lane < c) ? buf[wv][qi][lane] : 0ull;
#pragma unroll
      for (int kk = 2; kk <= 64; kk <<= 1) {
#pragma unroll
        for (int jj = 32; jj >= 1; jj >>= 1) {
          if (jj < kk) {
            const unsigned long long o = shflx64(val, jj);
            const bool up = ((lane & kk) == 0);
            const bool takeMax = (((lane & jj) != 0) == up);
            const unsigned long long mx = val > o ? val : o;
            const unsigned long long mn = val > o ? o : val;
            val = takeMax ? mx : mn;
          }
        }
      }
      const int rank = 63 - lane;
      if (rank < KMAXK) {
        const int m = 4095 - (int)(val & 0xFFFFFFFFull);
        knn[outbase + rank] = m;
      }
    } else if (c > 64 && c <= SCAP) {
      for (int r = 0; r < KMAXK; ++r) {
        unsigned long long lmax = 0ull;
        int lpos = -1;
        for (int p = lane; p < c; p += 64) {
          const unsigned long long q2 = buf[wv][qi][p];
          if (q2 > lmax) { lmax = q2; lpos = p; }
        }
        unsigned long long g = lmax;
#pragma unroll
        for (int s = 32; s >= 1; s >>= 1) {
          const unsigned long long o = shflx64(g, s);
          g = o > g ? o : g;
        }
        const unsigned long long pm = __ballot(lmax == g && lpos >= 0);
        const int lowlane = (int)(__ffsll((unsigned long long)pm) - 1);
        if (lane == lowlane) buf[wv][qi][lpos] = 0ull;
        if (lane == 0) knn[outbase + r] = 4095 - (int)(g & 0xFFFFFFFFull);
      }
    } else {
      unsigned long long prev = ~0ull;
      for (int r = 0; r < KMAXK; ++r) {
        unsigned long long best = 0ull;
        for (int j = 0; j < 64; ++j) {
          const int m = (j << 6) + lane;
          const float4v cc = xqb[m];
          float inner = cc[0] * qx[qi];
          inner = fmaf(cc[1], qy[qi], inner);
          inner = fmaf(cc[2], qz[qi], inner);
          const float pd = 2.0f * inner - qq[qi] - cc[3];
          const unsigned long long key =
              ((unsigned long long)ordkey(pd) << 32) | (unsigned)(4095 - m);
          if (key < prev && key > best) best = key;
        }
#pragma unroll
        for (int s = 32; s >= 1; s >>= 1) {
          const unsigned long long o = shflx64(best, s);
          best = o > best ? o : best;
        }
        if (lane == 0) knn[outbase + r] = 4095 - (int)(best & 0xFFFFFFFFull);
        prev = best;
      }
    }
  }
}

// ---------------- MLP epilogue (per point, math identical to round 6) ------
__device__ __forceinline__ void mlp_epilogue(float4v (&dfr)[2][4],
                                             const float* s2r, const float* be2r,
                                             const float* war, float sa, float ba0,
                                             float bga0, int q, int g,
                                             float* __restrict__ outp) {
  float part[2][4];
#pragma unroll
  for (int mt = 0; mt < 2; ++mt)
#pragma unroll
    for (int r = 0; r < 4; ++r) part[mt][r] = 0.f;
#pragma unroll
  for (int mt = 0; mt < 2; ++mt)
#pragma unroll
    for (int nt = 0; nt < 4; ++nt) {
      float4v d = dfr[mt][nt];
#pragma unroll
      for (int r = 0; r < 4; ++r) {
        float h2 = fmaf(d[r], s2r[nt], be2r[nt]);
        h2 = fmaxf(h2, 0.2f * h2);
        d[r] = h2;
        part[mt][r] = fmaf(war[nt], h2, part[mt][r]);
      }
      dfr[mt][nt] = d;
    }
#pragma unroll
  for (int mt = 0; mt < 2; ++mt)
#pragma unroll
    for (int r = 0; r < 4; ++r) {
      float p = part[mt][r];
      p += __shfl_xor(p, 1, 64);
      p += __shfl_xor(p, 2, 64);
      p += __shfl_xor(p, 4, 64);
      p += __shfl_xor(p, 8, 64);
      part[mt][r] = p;
    }

  const int mrow = g * 4;
  float sc0[4], sc1[4];
  float mloc = -3.0e38f;
#pragma unroll
  for (int r = 0; r < 4; ++r) {
    float a = fmaf(part[0][r] + ba0, sa, bga0);
    a = fmaxf(a, 0.2f * a);
    sc0[r] = a;
    mloc = fmaxf(mloc, a);
  }
#pragma unroll
  for (int r = 0; r < 4; ++r) {
    float a = fmaf(part[1][r] + ba0, sa, bga0);
    a = fmaxf(a, 0.2f * a);
    sc1[r] = a;
    if (mrow + r < 14) mloc = fmaxf(mloc, a);
  }
  mloc = fmaxf(mloc, __shfl_xor(mloc, 16, 64));
  mloc = fmaxf(mloc, __shfl_xor(mloc, 32, 64));

  float e0[4], e1[4];
  float l10 = 0.f, l20 = 0.f, l30 = 0.f;
#pragma unroll
  for (int r = 0; r < 4; ++r) {
    const float vv = expf(sc0[r] - mloc);
    e0[r] = vv;
    l30 += vv;
    l20 += vv;
    if (mrow + r < 10) l10 += vv;
  }
#pragma unroll
  for (int r = 0; r < 4; ++r) {
    const float vv = (mrow + r < 14) ? expf(sc1[r] - mloc) : 0.f;
    e1[r] = vv;
    l30 += vv;
    if (mrow + r < 4) l20 += vv;
  }
  l10 += __shfl_xor(l10, 16, 64); l10 += __shfl_xor(l10, 32, 64);
  l20 += __shfl_xor(l20, 16, 64); l20 += __shfl_xor(l20, 32, 64);
  l30 += __shfl_xor(l30, 16, 64); l30 += __shfl_xor(l30, 32, 64);
  const float i10 = 1.0f / l10, i20 = 1.0f / l20, i30 = 1.0f / l30;
  const float third = 1.0f / 3.0f;

  float wgt0[4], wgt1[4];
#pragma unroll
  for (int r = 0; r < 4; ++r) {
    wgt0[r] = e0[r] * (((mrow + r < 10) ? i10 : 0.f) + i20 + i30) * third;
    wgt1[r] = e1[r] * (((mrow + r < 4) ? i20 : 0.f) + i30) * third;
  }

  float acc[4] = {0.f, 0.f, 0.f, 0.f};
#pragma unroll
  for (int nt = 0; nt < 4; ++nt) {
#pragma unroll
    for (int r = 0; r < 4; ++r) {
      acc[nt] = fmaf(wgt0[r], dfr[0][nt][r], acc[nt]);
      acc[nt] = fmaf(wgt1[r], dfr[1][nt][r], acc[nt]);
    }
  }
#pragma unroll
  for (int nt = 0; nt < 4; ++nt) {
    acc[nt] += __shfl_xor(acc[nt], 16, 64);
    acc[nt] += __shfl_xor(acc[nt], 32, 64);
  }
  const float val = (g == 0) ? acc[0] : (g == 1) ? acc[1] : (g == 2) ? acc[2] : acc[3];
  outp[(size_t)(q + 16 * g) * NPT] = val;
}

// ---------------- Kernel 2: MFMA MLP, 2 points per wave --------------------
__global__ __launch_bounds__(256, 4) void pcc_mlp_mfma(
    const float4v* __restrict__ xq, const float* __restrict__ w1,
    const float* __restrict__ g1, const float* __restrict__ b1,
    const short8v* __restrict__ w2bf, const float* __restrict__ g2,
    const float* __restrict__ b2, const float* __restrict__ wa,
    const float* __restrict__ ba, const float* __restrict__ ga,
    const float* __restrict__ bga, const int* __restrict__ knn,
    float* __restrict__ out) {
  __shared__ float w1s[64][8];  // per ch: w1d*s1 (3), w1c*s1 (3), be1, 0
  const int tid = threadIdx.x;
  const float invs = 1.0f / sqrtf(1.0f + 1e-5f);
  for (int idx = tid; idx < 512; idx += 256) {
    const int c = idx >> 3, s = idx & 7;
    float v = 0.f;
    if (s < 6) v = w1[c * 6 + s] * (g1[c] * invs);
    else if (s == 6) v = b1[c];
    w1s[c][s] = v;
  }
  __syncthreads();

  const int wv = tid >> 6, lane = tid & 63;
  const int q = lane & 15, g = lane >> 4;
  const int wid = (blockIdx.x << 2) + wv;
  const int rowA = wid * 2;  // two consecutive points, same batch
  const int b = rowA >> 12;
  const int nA = rowA & (NPT - 1), nB = nA + 1;
  const float4v* xqb = xq + ((size_t)b << 12);

  const float4v qvA = xqb[nA];
  const float xnA0 = qvA[0], xnA1 = qvA[1], xnA2 = qvA[2];
  const float4v qvB = xqb[nB];
  const float xnB0 = qvB[0], xnB1 = qvB[1], xnB2 = qvB[2];

  const int jA0 = knn[rowA * 32 + q];
  const int jB0 = knn[(rowA + 1) * 32 + q];
  const float4v cA0 = xqb[jA0];
  const float4v cB0 = xqb[jB0];
  float aA1x = xnA0, aA1y = xnA1, aA1z = xnA2;  // pad row: d=0, finite
  float aB1x = xnB0, aB1y = xnB1, aB1z = xnB2;
  if (q < 14) {
    const int jA1 = knn[rowA * 32 + 16 + q];
    const int jB1 = knn[(rowA + 1) * 32 + 16 + q];
    const float4v cA1 = xqb[jA1];
    const float4v cB1 = xqb[jB1];
    aA1x = cA1[0]; aA1y = cA1[1]; aA1z = cA1[2];
    aB1x = cB1[0]; aB1y = cB1[1]; aB1z = cB1[2];
  }
  const float dA0x = cA0[0] - xnA0, dA0y = cA0[1] - xnA1, dA0z = cA0[2] - xnA2;
  const float dA1x = aA1x - xnA0, dA1y = aA1y - xnA1, dA1z = aA1z - xnA2;
  const float dB0x = cB0[0] - xnB0, dB0y = cB0[1] - xnB1, dB0z = cB0[2] - xnB2;
  const float dB1x = aB1x - xnB0, dB1y = aB1y - xnB1, dB1z = aB1z - xnB2;

  float4v dfrA[2][4], dfrB[2][4];
#pragma unroll
  for (int mt = 0; mt < 2; ++mt)
#pragma unroll
    for (int nt = 0; nt < 4; ++nt) {
      dfrA[mt][nt] = (float4v){0.f, 0.f, 0.f, 0.f};
      dfrB[mt][nt] = (float4v){0.f, 0.f, 0.f, 0.f};
    }

#pragma unroll
  for (int kt = 0; kt < 2; ++kt) {
    short8v bfk[4];
#pragma unroll
    for (int nt = 0; nt < 4; ++nt) bfk[nt] = w2bf[((kt << 2) + nt) * 64 + lane];
    int4v aA0i, aA1i, aB0i, aB1i;
#pragma unroll
    for (int e2 = 0; e2 < 4; ++e2) {
      float hA0[2], hA1[2], hB0[2], hB1[2];
#pragma unroll
      for (int u = 0; u < 2; ++u) {
        const int c = kt * 32 + g * 8 + e2 * 2 + u;
        const float4v wlo = *(const float4v*)&w1s[c][0];
        const float4v whi = *(const float4v*)&w1s[c][4];
        const float hcbA = fmaf(wlo[3], xnA0, fmaf(whi[0], xnA1, fmaf(whi[1], xnA2, whi[2])));
        float h = fmaf(wlo[0], dA0x, fmaf(wlo[1], dA0y, fmaf(wlo[2], dA0z, hcbA)));
        hA0[u] = fmaxf(h, 0.2f * h);
        h = fmaf(wlo[0], dA1x, fmaf(wlo[1], dA1y, fmaf(wlo[2], dA1z, hcbA)));
        hA1[u] = fmaxf(h, 0.2f * h);
        const float hcbB = fmaf(wlo[3], xnB0, fmaf(whi[0], xnB1, fmaf(whi[1], xnB2, whi[2])));
        h = fmaf(wlo[0], dB0x, fmaf(wlo[1], dB0y, fmaf(wlo[2], dB0z, hcbB)));
        hB0[u] = fmaxf(h, 0.2f * h);
        h = fmaf(wlo[0], dB1x, fmaf(wlo[1], dB1y, fmaf(wlo[2], dB1z, hcbB)));
        hB1[u] = fmaxf(h, 0.2f * h);
      }
      aA0i[e2] = cvtpk(hA0[0], hA0[1]);
      aA1i[e2] = cvtpk(hA1[0], hA1[1]);
      aB0i[e2] = cvtpk(hB0[0], hB0[1]);
      aB1i[e2] = cvtpk(hB1[0], hB1[1]);
    }
    const short8v afA0 = __builtin_bit_cast(short8v, aA0i);
    const short8v afA1 = __builtin_bit_cast(short8v, aA1i);
    const short8v afB0 = __builtin_bit_cast(short8v, aB0i);
    const short8v afB1 = __builtin_bit_cast(short8v, aB1i);
#pragma unroll
    for (int nt = 0; nt < 4; ++nt) {
      dfrA[0][nt] = __builtin_amdgcn_mfma_f32_16x16x32_bf16(afA0, bfk[nt], dfrA[0][nt], 0, 0, 0);
      dfrA[1][nt] = __builtin_amdgcn_mfma_f32_16x16x32_bf16(afA1, bfk[nt], dfrA[1][nt], 0, 0, 0);
      dfrB[0][nt] = __builtin_amdgcn_mfma_f32_16x16x32_bf16(afB0, bfk[nt], dfrB[0][nt], 0, 0, 0);
      dfrB[1][nt] = __builtin_amdgcn_mfma_f32_16x16x32_bf16(afB1, bfk[nt], dfrB[1][nt], 0, 0, 0);
    }
  }

  float s2r[4], be2r[4], war[4];
#pragma unroll
  for (int nt = 0; nt < 4; ++nt) {
    s2r[nt] = g2[q + 16 * nt] * invs;
    be2r[nt] = b2[q + 16 * nt];
    war[nt] = wa[q + 16 * nt];
  }
  const float sa = ga[0] * invs, ba0 = ba[0], bga0 = bga[0];

  float* outbB = out + ((size_t)b * 64) * NPT;
  mlp_epilogue(dfrA, s2r, be2r, war, sa, ba0, bga0, q, g, outbB + nA);
  mlp_epilogue(dfrB, s2r, be2r, war, sa, ba0, bga0, q, g, outbB + nB);
}

extern "C" void kernel_launch(void* const* d_in, const int* in_sizes, int n_in,
                              void* d_out, int out_size, void* d_ws, size_t ws_size,
                              hipStream_t stream) {
  const float* x = (const float*)d_in[0];
  const float* w1 = (const float*)d_in[1];
  const float* g1 = (const float*)d_in[2];
  const float* b1 = (const float*)d_in[3];
  const float* w2 = (const float*)d_in[4];
  const float* g2 = (const float*)d_in[5];
  const float* b2 = (const float*)d_in[6];
  const float* wa = (const float*)d_in[7];
  const float* ba = (const float*)d_in[8];
  const float* ga = (const float*)d_in[9];
  const float* bga = (const float*)d_in[10];
  float* out = (float*)d_out;

  float4v* xq = (float4v*)d_ws;                         // 512 KB
  int* knn = (int*)((char*)d_ws + ROWS * 16);           // 4 MB
  short8v* w2bf = (short8v*)((char*)d_ws + ROWS * 16 + ROWS * 32 * 4);  // 8 KB

  prep_kernel<<<dim3(ROWS / 256 + 1), dim3(256), 0, stream>>>(x, w2, xq, w2bf);
  knn_kernel<<<dim3(ROWS / (4 * QW)), dim3(256), 0, stream>>>(xq, knn);
  pcc_mlp_mfma<<<dim3(ROWS / 8), dim3(256), 0, stream>>>(
      xq, w1, g1, b1, w2bf, g2, b2, wa, ba, ga, bga, knn, out);
}

// Round 13
// 124.167 us; speedup vs baseline: 12.3136x; 1.0401x over previous
//
#include <hip/hip_runtime.h>
#include <math.h>

// PCCNet: KNN(30) + per-neighbor MLP(6->64->64) + 3-scale prefix softmax attention.
// Round 13: single change vs round 12 — knn __launch_bounds__(256,6) -> (256,8).
// Grid supplies 8 WG/CU; the old bound capped residency at 6 waves/SIMD and
// left latency exposed (Occupancy 48%, VALUBusy 65%). VGPR=28 fits 8 waves.

#define NB 8
#define NPT 4096
#define KMAXK 30
#define ROWS (NB * NPT)
#define QW 4     // queries per wave (knn)
#define SCAP 96  // survivor cap per query (observed ~48)

typedef __attribute__((ext_vector_type(8))) short short8v;
typedef __attribute__((ext_vector_type(4))) float float4v;
typedef __attribute__((ext_vector_type(2))) float float2v;
typedef __attribute__((ext_vector_type(4))) int int4v;

__device__ __forceinline__ unsigned long long shflx64(unsigned long long v, int m) {
  unsigned lo = (unsigned)__shfl_xor((int)(unsigned)(v & 0xFFFFFFFFull), m, 64);
  unsigned hi = (unsigned)__shfl_xor((int)(unsigned)(v >> 32), m, 64);
  return ((unsigned long long)hi << 32) | (unsigned long long)lo;
}

__device__ __forceinline__ short f2bf(float x) {  // f32 -> bf16 RNE
  unsigned u = __float_as_uint(x);
  return (short)((u + 0x7FFFu + ((u >> 16) & 1u)) >> 16);
}

__device__ __forceinline__ int cvtpk(float lo, float hi) {  // packed bf16 RNE
  int r;
  asm("v_cvt_pk_bf16_f32 %0, %1, %2" : "=v"(r) : "v"(lo), "v"(hi));
  return r;
}

__device__ __forceinline__ unsigned ordkey(float f) {  // monotonic u32 of f32
  const unsigned bits = __float_as_uint(f);
  return bits ^ ((unsigned)((int)bits >> 31) | 0x80000000u);
}

__device__ __forceinline__ float sbcast(float v) {  // force wave-uniform -> SGPR
  return __int_as_float(__builtin_amdgcn_readfirstlane(__float_as_int(v)));
}

// popcount of mask bits strictly below this lane (v_mbcnt_lo + v_mbcnt_hi).
__device__ __forceinline__ int mbcnt64(unsigned long long mask) {
  return (int)__builtin_amdgcn_mbcnt_hi(
      (unsigned)(mask >> 32),
      __builtin_amdgcn_mbcnt_lo((unsigned)(mask & 0xFFFFFFFFull), 0u));
}

// ---------------- Kernel 0: pack (x,y,z,|x|^2) + pack W2 bf16 fragments ----
__global__ __launch_bounds__(256) void prep_kernel(const float* __restrict__ x,
                                                   const float* __restrict__ w2,
                                                   float4v* __restrict__ xq,
                                                   short8v* __restrict__ w2bf) {
  const int i = blockIdx.x * 256 + threadIdx.x;
  if (i < ROWS) {
    const int b = i >> 12, m = i & (NPT - 1);
    const float* xb = x + (size_t)b * 3 * NPT;
    const float y0 = xb[m], y1 = xb[NPT + m], y2 = xb[2 * NPT + m];
    const float xx = y0 * y0 + y1 * y1 + y2 * y2;
    xq[i] = (float4v){y0, y1, y2, xx};
  }
  if (blockIdx.x == ROWS / 256) {
#pragma unroll
    for (int u = 0; u < 2; ++u) {
      const int v = threadIdx.x * 2 + u;
      const int lane = v & 63, fi = v >> 6;
      const int kt = fi >> 2, nt = fi & 3;
      const int q = lane & 15, g = lane >> 4;
      const float* src = w2 + (nt * 16 + q) * 64 + kt * 32 + g * 8;
      short8v tt;
#pragma unroll
      for (int e = 0; e < 8; ++e) tt[e] = f2bf(src[e]);
      w2bf[v] = tt;
    }
  }
}

// ---------------- Kernel 1: exact top-30 neighbor indices, 4 queries/wave --
__global__ __launch_bounds__(256, 8) void knn_kernel(const float4v* __restrict__ xq,
                                                     int* __restrict__ knn) {
  __shared__ unsigned long long buf[4][QW][SCAP];  // 12 KB
  const int wv = threadIdx.x >> 6;
  const int lane = threadIdx.x & 63;
  const int row0 = ((blockIdx.x << 2) + wv) * QW;
  const int b = row0 >> 12;
  const int n0 = row0 & (NPT - 1);
  const float4v* xqb = xq + ((size_t)b << 12);
  const float4v* pc = xqb + lane;

  float qx[QW], qy[QW], qz[QW], qq[QW];
#pragma unroll
  for (int qi = 0; qi < QW; ++qi) {
    const float4v qv = xqb[n0 + qi];
    qx[qi] = sbcast(qv[0]);
    qy[qi] = sbcast(qv[1]);
    qz[qi] = sbcast(qv[2]);
    qq[qi] = sbcast(qv[3]);
  }
  float2v qxp[2], qyp[2], qzp[2], qqp[2];
#pragma unroll
  for (int p = 0; p < 2; ++p) {
    qxp[p] = (float2v){qx[2 * p], qx[2 * p + 1]};
    qyp[p] = (float2v){qy[2 * p], qy[2 * p + 1]};
    qzp[p] = (float2v){qz[2 * p], qz[2 * p + 1]};
    qqp[p] = (float2v){qq[2 * p], qq[2 * p + 1]};
  }

  // ---- pass 1: per-query lane-max, unrolled x4 ----
  float2v kmaxp[2];
  kmaxp[0] = (float2v){-3.0e38f, -3.0e38f};
  kmaxp[1] = (float2v){-3.0e38f, -3.0e38f};
  for (int j = 0; j < 64; j += 4) {
    float4v cL[4];
#pragma unroll
    for (int u = 0; u < 4; ++u) cL[u] = pc[(size_t)(j + u) << 6];
#pragma unroll
    for (int u = 0; u < 4; ++u) {
      const float4v c = cL[u];
      const float2v cx = (float2v){c[0], c[0]};
      const float2v cy = (float2v){c[1], c[1]};
      const float2v cz = (float2v){c[2], c[2]};
      const float2v cw = (float2v){c[3], c[3]};
#pragma unroll
      for (int p = 0; p < 2; ++p) {
        float2v inner = cx * qxp[p];
        inner = __builtin_elementwise_fma(cy, qyp[p], inner);
        inner = __builtin_elementwise_fma(cz, qzp[p], inner);
        const float2v pd = (inner + inner) - qqp[p] - cw;
        kmaxp[p] = __builtin_elementwise_max(kmaxp[p], pd);
      }
    }
  }
  const float kmaxs[QW] = {kmaxp[0][0], kmaxp[0][1], kmaxp[1][0], kmaxp[1][1]};

  float thr[QW];
#pragma unroll
  for (int qi = 0; qi < QW; ++qi) {
    float v = kmaxs[qi];
#pragma unroll
    for (int kk = 2; kk <= 64; kk <<= 1) {
#pragma unroll
      for (int jj = 32; jj >= 1; jj >>= 1) {
        if (jj < kk) {
          const float o = __shfl_xor(v, jj, 64);
          const bool up = ((lane & kk) == 0);
          const bool takeMax = (((lane & jj) != 0) == up);
          v = takeMax ? fmaxf(v, o) : fminf(v, o);
        }
      }
    }
    thr[qi] = sbcast(__shfl(v, 34, 64)) - 1.0e-4f;  // eps: survivor superset only
  }

  // ---- pass 2: recompute + ballot-compact (mbcnt prefix rank), unrolled x4 ----
  int cnt[QW];
#pragma unroll
  for (int qi = 0; qi < QW; ++qi) cnt[qi] = 0;
  for (int j = 0; j < 64; j += 4) {
    float4v cL[4];
#pragma unroll
    for (int u = 0; u < 4; ++u) cL[u] = pc[(size_t)(j + u) << 6];
    float2v pdp[4][2];
#pragma unroll
    for (int u = 0; u < 4; ++u) {
      const float4v c = cL[u];
      const float2v cx = (float2v){c[0], c[0]};
      const float2v cy = (float2v){c[1], c[1]};
      const float2v cz = (float2v){c[2], c[2]};
      const float2v cw = (float2v){c[3], c[3]};
#pragma unroll
      for (int p = 0; p < 2; ++p) {
        float2v inner = cx * qxp[p];
        inner = __builtin_elementwise_fma(cy, qyp[p], inner);
        inner = __builtin_elementwise_fma(cz, qzp[p], inner);
        pdp[u][p] = (inner + inner) - qqp[p] - cw;
      }
    }
#pragma unroll
    for (int u = 0; u < 4; ++u) {
      const int m = ((j + u) << 6) + lane;
#pragma unroll
      for (int qi = 0; qi < QW; ++qi) {
        const float pd = pdp[u][qi >> 1][qi & 1];
        const bool pred = pd >= thr[qi];
        const unsigned long long mask = __ballot(pred);
        if (pred) {
          const int pos = cnt[qi] + mbcnt64(mask);
          if (pos < SCAP) {
            buf[wv][qi][pos] = ((unsigned long long)ordkey(pd) << 32) | (unsigned)(4095 - m);
          }
        }
        cnt[qi] += (int)__popcll(mask);
      }
    }
  }

  // ---- selection per query ----
#pragma unroll 1
  for (int qi = 0; qi < QW; ++qi) {
    const int c = cnt[qi];
    const int outbase = (row0 + qi) * 32;
    if (c >= KMAXK && c <= 64) {
      unsigned long long val = (lane < c) ? buf[wv][qi][lane] : 0ull;
#pragma unroll
      for (int kk = 2; kk <= 64; kk <<= 1) {
#pragma unroll
        for (int jj = 32; jj >= 1; jj >>= 1) {
          if (jj < kk) {
            const unsigned long long o = shflx64(val, jj);
            const bool up = ((lane & kk) == 0);
            const bool takeMax = (((lane & jj) != 0) == up);
            const unsigned long long mx = val > o ? val : o;
            const unsigned long long mn = val > o ? o : val;
            val = takeMax ? mx : mn;
          }
        }
      }
      const int rank = 63 - lane;
      if (rank < KMAXK) {
        const int m = 4095 - (int)(val & 0xFFFFFFFFull);
        knn[outbase + rank] = m;
      }
    } else if (c > 64 && c <= SCAP) {
      for (int r = 0; r < KMAXK; ++r) {
        unsigned long long lmax = 0ull;
        int lpos = -1;
        for (int p = lane; p < c; p += 64) {
          const unsigned long long q2 = buf[wv][qi][p];
          if (q2 > lmax) { lmax = q2; lpos = p; }
        }
        unsigned long long g = lmax;
#pragma unroll
        for (int s = 32; s >= 1; s >>= 1) {
          const unsigned long long o = shflx64(g, s);
          g = o > g ? o : g;
        }
        const unsigned long long pm = __ballot(lmax == g && lpos >= 0);
        const int lowlane = (int)(__ffsll((unsigned long long)pm) - 1);
        if (lane == lowlane) buf[wv][qi][lpos] = 0ull;
        if (lane == 0) knn[outbase + r] = 4095 - (int)(g & 0xFFFFFFFFull);
      }
    } else {
      unsigned long long prev = ~0ull;
      for (int r = 0; r < KMAXK; ++r) {
        unsigned long long best = 0ull;
        for (int j = 0; j < 64; ++j) {
          const int m = (j << 6) + lane;
          const float4v cc = xqb[m];
          float inner = cc[0] * qx[qi];
          inner = fmaf(cc[1], qy[qi], inner);
          inner = fmaf(cc[2], qz[qi], inner);
          const float pd = 2.0f * inner - qq[qi] - cc[3];
          const unsigned long long key =
              ((unsigned long long)ordkey(pd) << 32) | (unsigned)(4095 - m);
          if (key < prev && key > best) best = key;
        }
#pragma unroll
        for (int s = 32; s >= 1; s >>= 1) {
          const unsigned long long o = shflx64(best, s);
          best = o > best ? o : best;
        }
        if (lane == 0) knn[outbase + r] = 4095 - (int)(best & 0xFFFFFFFFull);
        prev = best;
      }
    }
  }
}

// ---------------- MLP epilogue (per point, math identical to round 6) ------
__device__ __forceinline__ void mlp_epilogue(float4v (&dfr)[2][4],
                                             const float* s2r, const float* be2r,
                                             const float* war, float sa, float ba0,
                                             float bga0, int q, int g,
                                             float* __restrict__ outp) {
  float part[2][4];
#pragma unroll
  for (int mt = 0; mt < 2; ++mt)
#pragma unroll
    for (int r = 0; r < 4; ++r) part[mt][r] = 0.f;
#pragma unroll
  for (int mt = 0; mt < 2; ++mt)
#pragma unroll
    for (int nt = 0; nt < 4; ++nt) {
      float4v d = dfr[mt][nt];
#pragma unroll
      for (int r = 0; r < 4; ++r) {
        float h2 = fmaf(d[r], s2r[nt], be2r[nt]);
        h2 = fmaxf(h2, 0.2f * h2);
        d[r] = h2;
        part[mt][r] = fmaf(war[nt], h2, part[mt][r]);
      }
      dfr[mt][nt] = d;
    }
#pragma unroll
  for (int mt = 0; mt < 2; ++mt)
#pragma unroll
    for (int r = 0; r < 4; ++r) {
      float p = part[mt][r];
      p += __shfl_xor(p, 1, 64);
      p += __shfl_xor(p, 2, 64);
      p += __shfl_xor(p, 4, 64);
      p += __shfl_xor(p, 8, 64);
      part[mt][r] = p;
    }

  const int mrow = g * 4;
  float sc0[4], sc1[4];
  float mloc = -3.0e38f;
#pragma unroll
  for (int r = 0; r < 4; ++r) {
    float a = fmaf(part[0][r] + ba0, sa, bga0);
    a = fmaxf(a, 0.2f * a);
    sc0[r] = a;
    mloc = fmaxf(mloc, a);
  }
#pragma unroll
  for (int r = 0; r < 4; ++r) {
    float a = fmaf(part[1][r] + ba0, sa, bga0);
    a = fmaxf(a, 0.2f * a);
    sc1[r] = a;
    if (mrow + r < 14) mloc = fmaxf(mloc, a);
  }
  mloc = fmaxf(mloc, __shfl_xor(mloc, 16, 64));
  mloc = fmaxf(mloc, __shfl_xor(mloc, 32, 64));

  float e0[4], e1[4];
  float l10 = 0.f, l20 = 0.f, l30 = 0.f;
#pragma unroll
  for (int r = 0; r < 4; ++r) {
    const float vv = expf(sc0[r] - mloc);
    e0[r] = vv;
    l30 += vv;
    l20 += vv;
    if (mrow + r < 10) l10 += vv;
  }
#pragma unroll
  for (int r = 0; r < 4; ++r) {
    const float vv = (mrow + r < 14) ? expf(sc1[r] - mloc) : 0.f;
    e1[r] = vv;
    l30 += vv;
    if (mrow + r < 4) l20 += vv;
  }
  l10 += __shfl_xor(l10, 16, 64); l10 += __shfl_xor(l10, 32, 64);
  l20 += __shfl_xor(l20, 16, 64); l20 += __shfl_xor(l20, 32, 64);
  l30 += __shfl_xor(l30, 16, 64); l30 += __shfl_xor(l30, 32, 64);
  const float i10 = 1.0f / l10, i20 = 1.0f / l20, i30 = 1.0f / l30;
  const float third = 1.0f / 3.0f;

  float wgt0[4], wgt1[4];
#pragma unroll
  for (int r = 0; r < 4; ++r) {
    wgt0[r] = e0[r] * (((mrow + r < 10) ? i10 : 0.f) + i20 + i30) * third;
    wgt1[r] = e1[r] * (((mrow + r < 4) ? i20 : 0.f) + i30) * third;
  }

  float acc[4] = {0.f, 0.f, 0.f, 0.f};
#pragma unroll
  for (int nt = 0; nt < 4; ++nt) {
#pragma unroll
    for (int r = 0; r < 4; ++r) {
      acc[nt] = fmaf(wgt0[r], dfr[0][nt][r], acc[nt]);
      acc[nt] = fmaf(wgt1[r], dfr[1][nt][r], acc[nt]);
    }
  }
#pragma unroll
  for (int nt = 0; nt < 4; ++nt) {
    acc[nt] += __shfl_xor(acc[nt], 16, 64);
    acc[nt] += __shfl_xor(acc[nt], 32, 64);
  }
  const float val = (g == 0) ? acc[0] : (g == 1) ? acc[1] : (g == 2) ? acc[2] : acc[3];
  outp[(size_t)(q + 16 * g) * NPT] = val;
}

// ---------------- Kernel 2: MFMA MLP, 2 points per wave --------------------
__global__ __launch_bounds__(256, 4) void pcc_mlp_mfma(
    const float4v* __restrict__ xq, const float* __restrict__ w1,
    const float* __restrict__ g1, const float* __restrict__ b1,
    const short8v* __restrict__ w2bf, const float* __restrict__ g2,
    const float* __restrict__ b2, const float* __restrict__ wa,
    const float* __restrict__ ba, const float* __restrict__ ga,
    const float* __restrict__ bga, const int* __restrict__ knn,
    float* __restrict__ out) {
  __shared__ float w1s[64][8];  // per ch: w1d*s1 (3), w1c*s1 (3), be1, 0
  const int tid = threadIdx.x;
  const float invs = 1.0f / sqrtf(1.0f + 1e-5f);
  for (int idx = tid; idx < 512; idx += 256) {
    const int c = idx >> 3, s = idx & 7;
    float v = 0.f;
    if (s < 6) v = w1[c * 6 + s] * (g1[c] * invs);
    else if (s == 6) v = b1[c];
    w1s[c][s] = v;
  }
  __syncthreads();

  const int wv = tid >> 6, lane = tid & 63;
  const int q = lane & 15, g = lane >> 4;
  const int wid = (blockIdx.x << 2) + wv;
  const int rowA = wid * 2;  // two consecutive points, same batch
  const int b = rowA >> 12;
  const int nA = rowA & (NPT - 1), nB = nA + 1;
  const float4v* xqb = xq + ((size_t)b << 12);

  const float4v qvA = xqb[nA];
  const float xnA0 = qvA[0], xnA1 = qvA[1], xnA2 = qvA[2];
  const float4v qvB = xqb[nB];
  const float xnB0 = qvB[0], xnB1 = qvB[1], xnB2 = qvB[2];

  const int jA0 = knn[rowA * 32 + q];
  const int jB0 = knn[(rowA + 1) * 32 + q];
  const float4v cA0 = xqb[jA0];
  const float4v cB0 = xqb[jB0];
  float aA1x = xnA0, aA1y = xnA1, aA1z = xnA2;  // pad row: d=0, finite
  float aB1x = xnB0, aB1y = xnB1, aB1z = xnB2;
  if (q < 14) {
    const int jA1 = knn[rowA * 32 + 16 + q];
    const int jB1 = knn[(rowA + 1) * 32 + 16 + q];
    const float4v cA1 = xqb[jA1];
    const float4v cB1 = xqb[jB1];
    aA1x = cA1[0]; aA1y = cA1[1]; aA1z = cA1[2];
    aB1x = cB1[0]; aB1y = cB1[1]; aB1z = cB1[2];
  }
  const float dA0x = cA0[0] - xnA0, dA0y = cA0[1] - xnA1, dA0z = cA0[2] - xnA2;
  const float dA1x = aA1x - xnA0, dA1y = aA1y - xnA1, dA1z = aA1z - xnA2;
  const float dB0x = cB0[0] - xnB0, dB0y = cB0[1] - xnB1, dB0z = cB0[2] - xnB2;
  const float dB1x = aB1x - xnB0, dB1y = aB1y - xnB1, dB1z = aB1z - xnB2;

  float4v dfrA[2][4], dfrB[2][4];
#pragma unroll
  for (int mt = 0; mt < 2; ++mt)
#pragma unroll
    for (int nt = 0; nt < 4; ++nt) {
      dfrA[mt][nt] = (float4v){0.f, 0.f, 0.f, 0.f};
      dfrB[mt][nt] = (float4v){0.f, 0.f, 0.f, 0.f};
    }

#pragma unroll
  for (int kt = 0; kt < 2; ++kt) {
    short8v bfk[4];
#pragma unroll
    for (int nt = 0; nt < 4; ++nt) bfk[nt] = w2bf[((kt << 2) + nt) * 64 + lane];
    int4v aA0i, aA1i, aB0i, aB1i;
#pragma unroll
    for (int e2 = 0; e2 < 4; ++e2) {
      float hA0[2], hA1[2], hB0[2], hB1[2];
#pragma unroll
      for (int u = 0; u < 2; ++u) {
        const int c = kt * 32 + g * 8 + e2 * 2 + u;
        const float4v wlo = *(const float4v*)&w1s[c][0];
        const float4v whi = *(const float4v*)&w1s[c][4];
        const float hcbA = fmaf(wlo[3], xnA0, fmaf(whi[0], xnA1, fmaf(whi[1], xnA2, whi[2])));
        float h = fmaf(wlo[0], dA0x, fmaf(wlo[1], dA0y, fmaf(wlo[2], dA0z, hcbA)));
        hA0[u] = fmaxf(h, 0.2f * h);
        h = fmaf(wlo[0], dA1x, fmaf(wlo[1], dA1y, fmaf(wlo[2], dA1z, hcbA)));
        hA1[u] = fmaxf(h, 0.2f * h);
        const float hcbB = fmaf(wlo[3], xnB0, fmaf(whi[0], xnB1, fmaf(whi[1], xnB2, whi[2])));
        h = fmaf(wlo[0], dB0x, fmaf(wlo[1], dB0y, fmaf(wlo[2], dB0z, hcbB)));
        hB0[u] = fmaxf(h, 0.2f * h);
        h = fmaf(wlo[0], dB1x, fmaf(wlo[1], dB1y, fmaf(wlo[2], dB1z, hcbB)));
        hB1[u] = fmaxf(h, 0.2f * h);
      }
      aA0i[e2] = cvtpk(hA0[0], hA0[1]);
      aA1i[e2] = cvtpk(hA1[0], hA1[1]);
      aB0i[e2] = cvtpk(hB0[0], hB0[1]);
      aB1i[e2] = cvtpk(hB1[0], hB1[1]);
    }
    const short8v afA0 = __builtin_bit_cast(short8v, aA0i);
    const short8v afA1 = __builtin_bit_cast(short8v, aA1i);
    const short8v afB0 = __builtin_bit_cast(short8v, aB0i);
    const short8v afB1 = __builtin_bit_cast(short8v, aB1i);
#pragma unroll
    for (int nt = 0; nt < 4; ++nt) {
      dfrA[0][nt] = __builtin_amdgcn_mfma_f32_16x16x32_bf16(afA0, bfk[nt], dfrA[0][nt], 0, 0, 0);
      dfrA[1][nt] = __builtin_amdgcn_mfma_f32_16x16x32_bf16(afA1, bfk[nt], dfrA[1][nt], 0, 0, 0);
      dfrB[0][nt] = __builtin_amdgcn_mfma_f32_16x16x32_bf16(afB0, bfk[nt], dfrB[0][nt], 0, 0, 0);
      dfrB[1][nt] = __builtin_amdgcn_mfma_f32_16x16x32_bf16(afB1, bfk[nt], dfrB[1][nt], 0, 0, 0);
    }
  }

  float s2r[4], be2r[4], war[4];
#pragma unroll
  for (int nt = 0; nt < 4; ++nt) {
    s2r[nt] = g2[q + 16 * nt] * invs;
    be2r[nt] = b2[q + 16 * nt];
    war[nt] = wa[q + 16 * nt];
  }
  const float sa = ga[0] * invs, ba0 = ba[0], bga0 = bga[0];

  float* outbB = out + ((size_t)b * 64) * NPT;
  mlp_epilogue(dfrA, s2r, be2r, war, sa, ba0, bga0, q, g, outbB + nA);
  mlp_epilogue(dfrB, s2r, be2r, war, sa, ba0, bga0, q, g, outbB + nB);
}

extern "C" void kernel_launch(void* const* d_in, const int* in_sizes, int n_in,
                              void* d_out, int out_size, void* d_ws, size_t ws_size,
                              hipStream_t stream) {
  const float* x = (const float*)d_in[0];
  const float* w1 = (const float*)d_in[1];
  const float* g1 = (const float*)d_in[2];
  const float* b1 = (const float*)d_in[3];
  const float* w2 = (const float*)d_in[4];
  const float* g2 = (const float*)d_in[5];
  const float* b2 = (const float*)d_in[6];
  const float* wa = (const float*)d_in[7];
  const float* ba = (const float*)d_in[8];
  const float* ga = (const float*)d_in[9];
  const float* bga = (const float*)d_in[10];
  float* out = (float*)d_out;

  float4v* xq = (float4v*)d_ws;                         // 512 KB
  int* knn = (int*)((char*)d_ws + ROWS * 16);           // 4 MB
  short8v* w2bf = (short8v*)((char*)d_ws + ROWS * 16 + ROWS * 32 * 4);  // 8 KB

  prep_kernel<<<dim3(ROWS / 256 + 1), dim3(256), 0, stream>>>(x, w2, xq, w2bf);
  knn_kernel<<<dim3(ROWS / (4 * QW)), dim3(256), 0, stream>>>(xq, knn);
  pcc_mlp_mfma<<<dim3(ROWS / 8), dim3(256), 0, stream>>>(
      xq, w1, g1, b1, w2bf, g2, b2, wa, ba, ga, bga, knn, out);
}